// Round 4
// baseline (150.672 us; speedup 1.0000x reference)
//
#include <hip/hip_runtime.h>
#include <math.h>

#define DK 32
#define OUT_DIM 32

typedef float    f32x4 __attribute__((ext_vector_type(4)));
typedef float    f32x2 __attribute__((ext_vector_type(2)));
typedef _Float16 h2    __attribute__((ext_vector_type(2)));
typedef _Float16 h8    __attribute__((ext_vector_type(8)));

#if __has_builtin(__builtin_amdgcn_exp2f)
#define EXP2F(x) __builtin_amdgcn_exp2f(x)
#else
#define EXP2F(x) exp2f(x)
#endif

__device__ __forceinline__ h2 as_h2(unsigned u) {
    union { unsigned u; h2 h; } v; v.u = u; return v.h;
}
__device__ __forceinline__ unsigned as_u32(h2 h) {
    union { unsigned u; h2 h; } v; v.h = h; return v.u;
}

// ---- fp8 e4m3 codec --------------------------------------------------------
// HW path on gfx950 (v_cvt_pk_fp8_f32 / v_cvt_pk_f32_fp8). Software fallback
// is self-consistent (encode+decode pair) so correctness never depends on
// format details; only one path is ever compiled.
#if __has_builtin(__builtin_amdgcn_cvt_pk_fp8_f32) && \
    __has_builtin(__builtin_amdgcn_cvt_pk_f32_fp8)
__device__ __forceinline__ unsigned fp8x4_pack(float4 f) {
    int d = 0;
    d = __builtin_amdgcn_cvt_pk_fp8_f32(f.x, f.y, d, false);
    d = __builtin_amdgcn_cvt_pk_fp8_f32(f.z, f.w, d, true);
    return (unsigned)d;
}
__device__ __forceinline__ f32x2 fp8x2_lo(unsigned d) {
    return __builtin_amdgcn_cvt_pk_f32_fp8((int)d, false);
}
__device__ __forceinline__ f32x2 fp8x2_hi(unsigned d) {
    return __builtin_amdgcn_cvt_pk_f32_fp8((int)d, true);
}
#else
__device__ __forceinline__ unsigned fp8_enc1(float f) {
    const unsigned s = (__float_as_uint(f) >> 24) & 0x80u;
    float a = fabsf(f);
    if (!(a > 0.0f)) return s;
    if (a >= 448.0f) return s | 0x7Eu;
    if (a < 0.015625f) {                       // subnormal, step 2^-9
        int m = (int)rintf(ldexpf(a, 9));
        if (m >= 8) return s | 0x08u;          // rounds up to min normal
        return s | (unsigned)m;
    }
    int ee = (int)floorf(log2f(a));
    float mant = ldexpf(a, -ee);               // [1,2)
    int m3 = (int)rintf((mant - 1.0f) * 8.0f);
    if (m3 == 8) { m3 = 0; ++ee; }
    if (ee > 8) return s | 0x7Eu;
    return s | ((unsigned)(ee + 7) << 3) | (unsigned)m3;
}
__device__ __forceinline__ float fp8_dec1(unsigned b) {
    const float sg = (b & 0x80u) ? -1.0f : 1.0f;
    const int e = (int)((b >> 3) & 0xFu);
    const int m = (int)(b & 0x7u);
    if (e == 0) return sg * ldexpf((float)m, -9);
    return sg * ldexpf(1.0f + (float)m * 0.125f, e - 7);
}
__device__ __forceinline__ unsigned fp8x4_pack(float4 f) {
    return fp8_enc1(f.x) | (fp8_enc1(f.y) << 8) |
           (fp8_enc1(f.z) << 16) | (fp8_enc1(f.w) << 24);
}
__device__ __forceinline__ f32x2 fp8x2_lo(unsigned d) {
    f32x2 r; r.x = fp8_dec1(d & 0xFFu); r.y = fp8_dec1((d >> 8) & 0xFFu);
    return r;
}
__device__ __forceinline__ f32x2 fp8x2_hi(unsigned d) {
    f32x2 r; r.x = fp8_dec1((d >> 16) & 0xFFu); r.y = fp8_dec1(d >> 24);
    return r;
}
#endif

// R15 prep: int4-vectorized dst boundary scan (4 edges/thread) + split-table
// pack: K8[t] = 4 x fp8(K[s][4c..4c+3]) (dword; 32 B/node row, 3.2 MB table),
// V16[t] = 4 x f16(V[s][4c..4c+3]) (uint2; 64 B/node aligned row, 6.4 MB).
// Rationale (R14 post-mortem): the fused kernel is bound by the L2-miss
// gather path (~86 MB @ ~1.9 TB/s, invariant across 3 scheduling rewrites).
// Shrinking the gathered footprint is the only lever: V -> 1 line/edge,
// K table near-L2-resident.
__global__ void prep_kernel(const int* __restrict__ dst,
                            const float4* __restrict__ K4,
                            const float4* __restrict__ V4,
                            int E, int N,
                            int* __restrict__ row_ptr,
                            unsigned* __restrict__ K8,
                            uint2* __restrict__ V16) {
    const int t  = blockIdx.x * blockDim.x + threadIdx.x;
    const int e0 = t * 4;
    if (e0 < E) {
        int cur[4];
        if (e0 + 4 <= E) {
            const int4 dd = *(const int4*)(dst + e0);
            cur[0] = dd.x; cur[1] = dd.y; cur[2] = dd.z; cur[3] = dd.w;
        } else {
#pragma unroll
            for (int k = 0; k < 4; ++k)
                cur[k] = (e0 + k < E) ? dst[e0 + k] : 0;
        }
        int prev = (e0 == 0) ? -1 : dst[e0 - 1];
#pragma unroll
        for (int k = 0; k < 4; ++k) {
            const int ee = e0 + k;
            if (ee < E) {
                for (int j = prev + 1; j <= cur[k]; ++j) row_ptr[j] = ee;
                if (ee == E - 1)
                    for (int j = cur[k] + 1; j <= N; ++j) row_ptr[j] = E;
                prev = cur[k];
            }
        }
    }
    if (t < N * 8) {
        const float4 kf = K4[t];
        const float4 vf = V4[t];
        K8[t] = fp8x4_pack(kf);
        h2 v01, v23;
        v01.x = (_Float16)vf.x;  v01.y = (_Float16)vf.y;
        v23.x = (_Float16)vf.z;  v23.y = (_Float16)vf.w;
        uint2 o; o.x = as_u32(v01); o.y = as_u32(v23);
        V16[t] = o;
    }
}

// Fallback-path row_ptr builder (ws too small for packed tables).
__global__ void build_row_ptr_kernel(const int* __restrict__ dst, int E, int N,
                                     int* __restrict__ row_ptr) {
    int e = blockIdx.x * blockDim.x + threadIdx.x;
    if (e >= E) return;
    int cur  = dst[e];
    int prev = (e == 0) ? -1 : dst[e - 1];
    for (int j = prev + 1; j <= cur; ++j) row_ptr[j] = e;
    if (e == E - 1) {
        for (int j = cur + 1; j <= N; ++j) row_ptr[j] = E;
    }
}

// R15: R14 structure (one node/wave, straight-line gather prologue) with the
// split fp8-K / f16-V tables. Per edge the gather is now 1x dword (K, hot
// 3.2 MB table) + 1x dwordx2 (V, one 64 B line) instead of one 128 B row
// over 2 lines. Dot is f32 (q pre-scaled by log2e/32, weight = exp2);
// V/weight accumulation upgraded f16 -> f32 (removes old accum error,
// offsetting fp8 score noise). Verified MFMA projection epilogue unchanged.
__global__ __launch_bounds__(512) void gat_fused_kernel(
    const float* __restrict__ X, const unsigned* __restrict__ K8,
    const uint2* __restrict__ V16,
    const float* __restrict__ Wo, const float* __restrict__ bo,
    const int* __restrict__ src, const int* __restrict__ row_ptr,
    float* __restrict__ out, int N) {

    __shared__ uint4 s_part[16 * 17];   // 16-row A-tile, row stride 17 (pad)

    const int tid  = threadIdx.x;
    const int w    = tid >> 6;    // wave 0..7 = node offset in block
    const int lane = tid & 63;
    const int g    = lane >> 3;   // edge slot 0..7
    const int c    = lane & 7;    // dim chunk 0..7

    const int n_blk = blockIdx.x * 8;
    const int n     = n_blk + w;

    // zero A-tile rows 8..15 (read by MFMA, never stored)
    if (tid < 136) {
        uint4 z; z.x = 0; z.y = 0; z.z = 0; z.w = 0;
        s_part[136 + tid] = z;
    }

    // wave-uniform segment bounds (readfirstlane -> SALU)
    const int B    = __builtin_amdgcn_readfirstlane(row_ptr[min(n, N)]);
    const int En   = __builtin_amdgcn_readfirstlane(row_ptr[min(n + 1, N)]);
    const int deg  = En - B;
    const int dcap = max(En - 1, 0);
    const int T    = (deg + 7) >> 3;

    const float scale = 0.03125f * 1.44269504f;  // 1/dk * log2(e) for exp2
    float4 qf = ((const float4*)X)[min(n, N - 1) * 8 + c];
    qf.x *= scale; qf.y *= scale; qf.z *= scale; qf.w *= scale;

    float l = 0.0f;
    f32x4 acc = {0.0f, 0.0f, 0.0f, 0.0f};

    auto step = [&](unsigned kd, uint2 vv, int t) {
        const f32x2 klo = fp8x2_lo(kd);
        const f32x2 khi = fp8x2_hi(kd);
        float p = fmaf(qf.x, klo.x, fmaf(qf.y, klo.y,
                  fmaf(qf.z, khi.x, qf.w * khi.y)));
        p += __shfl_xor(p, 1);
        p += __shfl_xor(p, 2);
        p += __shfl_xor(p, 4);
        const float wt = (t * 8 + g < deg) ? EXP2F(p) : 0.0f;
        l += wt;
        const h2 v01 = as_h2(vv.x);
        const h2 v23 = as_h2(vv.y);
        acc.x = fmaf(wt, (float)v01.x, acc.x);
        acc.y = fmaf(wt, (float)v01.y, acc.y);
        acc.z = fmaf(wt, (float)v23.x, acc.z);
        acc.w = fmaf(wt, (float)v23.y, acc.w);
    };

    if (T > 0) {
        const int base = B + g;
        // all src loads issued up front (independent)
        const int s0 = src[min(base, dcap)];
        int s1 = 0, s2 = 0, s3 = 0;
        if (T > 1) s1 = src[min(base + 8,  dcap)];
        if (T > 2) s2 = src[min(base + 16, dcap)];
        if (T > 3) s3 = src[min(base + 24, dcap)];
        // all K/V gathers issued together (independent chains)
        unsigned k0 = 0, k1 = 0, k2 = 0, k3 = 0;
        uint2 v0 = {0, 0}, v1 = {0, 0}, v2 = {0, 0}, v3 = {0, 0};
        k0 = K8[s0 * 8 + c];               v0 = V16[s0 * 8 + c];
        if (T > 1) { k1 = K8[s1 * 8 + c];  v1 = V16[s1 * 8 + c]; }
        if (T > 2) { k2 = K8[s2 * 8 + c];  v2 = V16[s2 * 8 + c]; }
        if (T > 3) { k3 = K8[s3 * 8 + c];  v3 = V16[s3 * 8 + c]; }

        step(k0, v0, 0);
        if (T > 1) step(k1, v1, 1);
        if (T > 2) step(k2, v2, 2);
        if (T > 3) step(k3, v3, 3);

        // rare tail (deg > 32): serial, correctness path
        for (int t = 4; t < T; ++t) {
            const int sx = src[min(B + t * 8 + g, dcap)];
            step(K8[sx * 8 + c], V16[sx * 8 + c], t);
        }
    }

    // per-node reduction: l over all slots; acc folded to 4 slot-pair partials
    l     += __shfl_xor(l, 8);
    acc.x += __shfl_xor(acc.x, 8);
    acc.y += __shfl_xor(acc.y, 8);
    acc.z += __shfl_xor(acc.z, 8);
    acc.w += __shfl_xor(acc.w, 8);
    l += __shfl_xor(l, 16);
    l += __shfl_xor(l, 32);

    const float inv = (deg > 0) ? (1.0f / l) : 0.0f;
    h2 o01, o23;
    o01.x = (_Float16)(acc.x * inv);  o01.y = (_Float16)(acc.y * inv);
    o23.x = (_Float16)(acc.z * inv);  o23.y = (_Float16)(acc.w * inv);

    if ((g & 1) == 0) {                  // even slots hold pair sums
        unsigned* part32 = (unsigned*)s_part;
        const int off = w * 68 + (g >> 1) * 16 + c * 2;   // uint32 units
        part32[off]     = as_u32(o01);
        part32[off + 1] = as_u32(o23);
    }

    __syncthreads();

    // wave 0: projection for the block's 8 nodes via 16x16x32 f16 MFMA
    // (A rows 8..15 are zero; C rows 8..15 discarded)
    if (w == 0) {
        const int quad = lane >> 4;   // 0..3
        const int col  = lane & 15;

        union BF { h8 v; _Float16 u[8]; };
        BF bf0, bf1;
#pragma unroll
        for (int j2 = 0; j2 < 8; ++j2) {
            bf0.u[j2] = (_Float16)Wo[(quad * 8 + j2) * OUT_DIM + col];
            bf1.u[j2] = (_Float16)Wo[(quad * 8 + j2) * OUT_DIM + 16 + col];
        }
        const float bias0 = bo[col];
        const float bias1 = bo[16 + col];

        union AF { uint4 u; h8 v; };
        f32x4 C0 = {bias0, bias0, bias0, bias0};
        f32x4 C1 = {bias1, bias1, bias1, bias1};
#pragma unroll
        for (int cc = 0; cc < 4; ++cc) {
            AF a;
            a.u = s_part[col * 17 + cc * 4 + quad];      // ds_read_b128
            C0 = __builtin_amdgcn_mfma_f32_16x16x32_f16(a.v, bf0.v, C0, 0, 0, 0);
            C1 = __builtin_amdgcn_mfma_f32_16x16x32_f16(a.v, bf1.v, C1, 0, 0, 0);
        }
        // C/D layout: col = lane&15, row = quad*4 + reg (verified mapping)
        if (quad < 2) {                 // only rows 0..7 are real nodes
#pragma unroll
            for (int r = 0; r < 4; ++r) {
                const int n2 = n_blk + quad * 4 + r;
                if (n2 < N) {
                    out[n2 * OUT_DIM + col]      = C0[r];
                    out[n2 * OUT_DIM + 16 + col] = C1[r];
                }
            }
        }
    }
}

// ---- fallback (R4-proven fp32 path, used only if ws too small) ------------
__global__ __launch_bounds__(256) void gat_node_f32_kernel(
    const float* __restrict__ X, const float* __restrict__ Km,
    const float* __restrict__ Vm, const float* __restrict__ Wo,
    const float* __restrict__ bo, const int* __restrict__ src,
    const int* __restrict__ row_ptr, float* __restrict__ out, int N) {
    const int tid  = threadIdx.x;
    const int wave = tid >> 6;
    const int lane = tid & 63;
    const int g    = lane >> 3;
    const int c    = lane & 7;
    const int j    = lane & 31;
    const int half = lane >> 5;
    const int n = blockIdx.x * 4 + wave;
    if (n >= N) return;
    const int begin = row_ptr[n];
    const int end   = row_ptr[n + 1];
    const float4* X4 = (const float4*)X;
    const float4* K4 = (const float4*)Km;
    const float4* V4 = (const float4*)Vm;
    const float4 q4 = X4[n * 8 + c];
    float  l   = 0.0f;
    float4 acc = make_float4(0.0f, 0.0f, 0.0f, 0.0f);
    for (int e0 = begin; e0 < end; e0 += 16) {
        const int  ea = e0 + g;
        const int  eb = ea + 8;
        const bool va = ea < end;
        const bool vb = eb < end;
        const int sa = src[min(ea, end - 1)];
        const int sb = src[min(eb, end - 1)];
        const float4 ka  = K4[sa * 8 + c];
        const float4 kb  = K4[sb * 8 + c];
        const float4 vva = V4[sa * 8 + c];
        const float4 vvb = V4[sb * 8 + c];
        float pa = fmaf(ka.x, q4.x, fmaf(ka.y, q4.y, fmaf(ka.z, q4.z, ka.w * q4.w)));
        float pb = fmaf(kb.x, q4.x, fmaf(kb.y, q4.y, fmaf(kb.z, q4.z, kb.w * q4.w)));
        pa += __shfl_xor(pa, 1);  pb += __shfl_xor(pb, 1);
        pa += __shfl_xor(pa, 2);  pb += __shfl_xor(pb, 2);
        pa += __shfl_xor(pa, 4);  pb += __shfl_xor(pb, 4);
        const float wa = va ? __expf(pa * 0.03125f) : 0.0f;
        const float wb = vb ? __expf(pb * 0.03125f) : 0.0f;
        l += wa + wb;
        acc.x = fmaf(wa, vva.x, acc.x);  acc.y = fmaf(wa, vva.y, acc.y);
        acc.z = fmaf(wa, vva.z, acc.z);  acc.w = fmaf(wa, vva.w, acc.w);
        acc.x = fmaf(wb, vvb.x, acc.x);  acc.y = fmaf(wb, vvb.y, acc.y);
        acc.z = fmaf(wb, vvb.z, acc.z);  acc.w = fmaf(wb, vvb.w, acc.w);
    }
#pragma unroll
    for (int m = 8; m <= 32; m <<= 1) {
        l     += __shfl_xor(l, m);
        acc.x += __shfl_xor(acc.x, m);
        acc.y += __shfl_xor(acc.y, m);
        acc.z += __shfl_xor(acc.z, m);
        acc.w += __shfl_xor(acc.w, m);
    }
    const float inv = (end > begin) ? (1.0f / l) : 0.0f;
    float ag[4] = {acc.x, acc.y, acc.z, acc.w};
    float s = 0.0f;
#pragma unroll
    for (int k = 0; k < 32; ++k) {
        const float a = __int_as_float(
            __builtin_amdgcn_readlane(__float_as_int(ag[k & 3]), k >> 2));
        s = fmaf(a, Wo[k * OUT_DIM + j], s);
    }
    if (half == 0) {
        out[n * OUT_DIM + j] = fmaf(s, inv, bo[j]);
    }
}

extern "C" void kernel_launch(void* const* d_in, const int* in_sizes, int n_in,
                              void* d_out, int out_size, void* d_ws, size_t ws_size,
                              hipStream_t stream) {
    const float* X  = (const float*)d_in[0];
    const float* Km = (const float*)d_in[1];
    const float* Vm = (const float*)d_in[2];
    const float* Wo = (const float*)d_in[3];
    const float* bo = (const float*)d_in[4];
    const int* src  = (const int*)d_in[5];
    const int* dst  = (const int*)d_in[6];

    const int N = in_sizes[0] / DK;
    const int E = in_sizes[5];

    int* row_ptr = (int*)d_ws;                              // (N+1) ints
    const size_t k8_off  = (((size_t)(N + 1) * 4) + 127) & ~(size_t)127;
    const size_t v16_off = ((k8_off + (size_t)N * 32) + 127) & ~(size_t)127;
    unsigned* K8 = (unsigned*)((char*)d_ws + k8_off);       // N*8 dwords
    uint2*   V16 = (uint2*)((char*)d_ws + v16_off);         // N*8 uint2
    const size_t need = v16_off + (size_t)N * 64;
    float* out = (float*)d_out;

    const int tb = 256;

    if (ws_size >= need) {
        const int nE4   = (E + 3) / 4;       // 4 edges per thread (dst scan)
        const int total = N * 8;             // one thread per node-chunk
        const int prep_n = (nE4 > total) ? nE4 : total;
        prep_kernel<<<(prep_n + tb - 1) / tb, tb, 0, stream>>>(
            dst, (const float4*)Km, (const float4*)Vm, E, N,
            row_ptr, K8, V16);
        const int grid = (N + 7) / 8;       // 8 nodes per block, 1 per wave
        gat_fused_kernel<<<grid, 512, 0, stream>>>(X, K8, V16, Wo, bo,
                                                   src, row_ptr, out, N);
    } else {
        build_row_ptr_kernel<<<(E + tb - 1) / tb, tb, 0, stream>>>(dst, E, N, row_ptr);
        const int grid = (N + 3) / 4;
        gat_node_f32_kernel<<<grid, 256, 0, stream>>>(X, Km, Vm, Wo, bo,
                                                      src, row_ptr, out, N);
    }
}

// Round 5
// 146.400 us; speedup vs baseline: 1.0292x; 1.0292x over previous
//
#include <hip/hip_runtime.h>
#include <math.h>

#define DK 32
#define OUT_DIM 32

typedef float    f32x4 __attribute__((ext_vector_type(4)));
typedef _Float16 h2    __attribute__((ext_vector_type(2)));
typedef _Float16 h8    __attribute__((ext_vector_type(8)));

#if __has_builtin(__builtin_amdgcn_exp2f)
#define EXP2F(x) __builtin_amdgcn_exp2f(x)
#else
#define EXP2F(x) exp2f(x)
#endif

__device__ __forceinline__ h2 as_h2(unsigned u) {
    union { unsigned u; h2 h; } v; v.u = u; return v.h;
}
__device__ __forceinline__ unsigned as_u32(h2 h) {
    union { unsigned u; h2 h; } v; v.h = h; return v.u;
}

// ---- int8 quantizer (per-node scale) --------------------------------------
__device__ __forceinline__ unsigned q8b(float x, float r) {
    int i = (int)rintf(x * r);
    i = min(127, max(-127, i));
    return (unsigned)(i & 255);
}
__device__ __forceinline__ unsigned pack8x4(float4 f, float r) {
    return q8b(f.x, r) | (q8b(f.y, r) << 8) |
           (q8b(f.z, r) << 16) | (q8b(f.w, r) << 24);
}

// R16 prep.
// Post-mortem R15: FETCH rose 86->129 MB because splitting tables doubled
// the random line-touches/edge (TCC line = 128 B; fetch = touches x miss x
// 128 B fits both R14 and R15 exactly). Fix: ONE 64 B row per node holding
// BOTH K and V as int8 with per-node scales -> 6.4 MB table (50 K lines,
// 2 nodes/line), one touch stream, miss rate collapses. Scales (2 x f16 per
// node, 400 KB) live in a separate L2-resident side table.
// Row layout: 8 x uint2 chunks; chunk c = {K[4c..4c+3] int8, V[4c..4c+3]
// int8}. Scan part (int4, 4 edges/thread) unchanged.
__global__ void prep_kernel(const int* __restrict__ dst,
                            const float4* __restrict__ K4,
                            const float4* __restrict__ V4,
                            int E, int N,
                            int* __restrict__ row_ptr,
                            uint2* __restrict__ ROW,
                            unsigned* __restrict__ SC) {
    const int t  = blockIdx.x * blockDim.x + threadIdx.x;
    const int e0 = t * 4;
    if (e0 < E) {
        int cur[4];
        if (e0 + 4 <= E) {
            const int4 dd = *(const int4*)(dst + e0);
            cur[0] = dd.x; cur[1] = dd.y; cur[2] = dd.z; cur[3] = dd.w;
        } else {
#pragma unroll
            for (int k = 0; k < 4; ++k)
                cur[k] = (e0 + k < E) ? dst[e0 + k] : 0;
        }
        int prev = (e0 == 0) ? -1 : dst[e0 - 1];
#pragma unroll
        for (int k = 0; k < 4; ++k) {
            const int ee = e0 + k;
            if (ee < E) {
                for (int j = prev + 1; j <= cur[k]; ++j) row_ptr[j] = ee;
                if (ee == E - 1)
                    for (int j = cur[k] + 1; j <= N; ++j) row_ptr[j] = E;
                prev = cur[k];
            }
        }
    }
    if (t < N) {
        float4 kf[8], vf[8];
#pragma unroll
        for (int u = 0; u < 8; ++u) { kf[u] = K4[t * 8 + u]; vf[u] = V4[t * 8 + u]; }
        float mk = 0.0f, mv = 0.0f;
#pragma unroll
        for (int u = 0; u < 8; ++u) {
            mk = fmaxf(mk, fmaxf(fmaxf(fabsf(kf[u].x), fabsf(kf[u].y)),
                                 fmaxf(fabsf(kf[u].z), fabsf(kf[u].w))));
            mv = fmaxf(mv, fmaxf(fmaxf(fabsf(vf[u].x), fabsf(vf[u].y)),
                                 fmaxf(fabsf(vf[u].z), fabsf(vf[u].w))));
        }
        const float rk = (mk > 0.0f) ? 127.0f / mk : 0.0f;
        const float rv = (mv > 0.0f) ? 127.0f / mv : 0.0f;
        uint4* o4 = (uint4*)(ROW + t * 8);
#pragma unroll
        for (int u2 = 0; u2 < 4; ++u2) {
            uint4 o;
            o.x = pack8x4(kf[2 * u2],     rk);
            o.y = pack8x4(vf[2 * u2],     rv);
            o.z = pack8x4(kf[2 * u2 + 1], rk);
            o.w = pack8x4(vf[2 * u2 + 1], rv);
            o4[u2] = o;
        }
        h2 s;
        s.x = (_Float16)(mk * (1.0f / 127.0f));   // K dequant scale
        s.y = (_Float16)(mv * (1.0f / 127.0f));   // V dequant scale
        SC[t] = as_u32(s);
    }
}

// Fallback-path row_ptr builder (ws too small for packed tables).
__global__ void build_row_ptr_kernel(const int* __restrict__ dst, int E, int N,
                                     int* __restrict__ row_ptr) {
    int e = blockIdx.x * blockDim.x + threadIdx.x;
    if (e >= E) return;
    int cur  = dst[e];
    int prev = (e == 0) ? -1 : dst[e - 1];
    for (int j = prev + 1; j <= cur; ++j) row_ptr[j] = e;
    if (e == E - 1) {
        for (int j = cur + 1; j <= N; ++j) row_ptr[j] = E;
    }
}

// R16: R14 structure (one node/wave, straight-line gather prologue), gather
// is ONE uint2 (8 B of the 64 B row; 8 lanes cover the row -> 1 line/edge)
// + one dword from the hot 400 KB scale table. int8 decode in f32, score =
// sK * (q.k8) with q pre-scaled by log2e/32 (weight = exp2), V accum f32
// with sV folded into the weight. Verified MFMA projection epilogue kept.
__global__ __launch_bounds__(512) void gat_fused_kernel(
    const float* __restrict__ X, const uint2* __restrict__ ROW,
    const unsigned* __restrict__ SC,
    const float* __restrict__ Wo, const float* __restrict__ bo,
    const int* __restrict__ src, const int* __restrict__ row_ptr,
    float* __restrict__ out, int N) {

    __shared__ uint4 s_part[16 * 17];   // 16-row A-tile, row stride 17 (pad)

    const int tid  = threadIdx.x;
    const int w    = tid >> 6;    // wave 0..7 = node offset in block
    const int lane = tid & 63;
    const int g    = lane >> 3;   // edge slot 0..7
    const int c    = lane & 7;    // dim chunk 0..7

    const int n_blk = blockIdx.x * 8;
    const int n     = n_blk + w;

    // zero A-tile rows 8..15 (read by MFMA, never stored)
    if (tid < 136) {
        uint4 z; z.x = 0; z.y = 0; z.z = 0; z.w = 0;
        s_part[136 + tid] = z;
    }

    // wave-uniform segment bounds (readfirstlane -> SALU)
    const int B    = __builtin_amdgcn_readfirstlane(row_ptr[min(n, N)]);
    const int En   = __builtin_amdgcn_readfirstlane(row_ptr[min(n + 1, N)]);
    const int deg  = En - B;
    const int dcap = max(En - 1, 0);
    const int T    = (deg + 7) >> 3;

    const float scale = 0.03125f * 1.44269504f;  // 1/dk * log2(e) for exp2
    float4 qf = ((const float4*)X)[min(n, N - 1) * 8 + c];
    qf.x *= scale; qf.y *= scale; qf.z *= scale; qf.w *= scale;

    float l = 0.0f;
    f32x4 acc = {0.0f, 0.0f, 0.0f, 0.0f};

    auto step = [&](uint2 rv, unsigned sc, int t) {
        const h2 sch = as_h2(sc);
        const float sK = (float)sch.x;
        const float sV = (float)sch.y;
        const int b0 = (int)(char)(rv.x);
        const int b1 = (int)(char)(rv.x >> 8);
        const int b2 = (int)(char)(rv.x >> 16);
        const int b3 = (int)(char)(rv.x >> 24);
        float p = fmaf(qf.x, (float)b0, fmaf(qf.y, (float)b1,
                  fmaf(qf.z, (float)b2, qf.w * (float)b3)));
        p += __shfl_xor(p, 1);
        p += __shfl_xor(p, 2);
        p += __shfl_xor(p, 4);
        p *= sK;
        const float wt = (t * 8 + g < deg) ? EXP2F(p) : 0.0f;
        l += wt;
        const float wv = wt * sV;
        const int c0 = (int)(char)(rv.y);
        const int c1 = (int)(char)(rv.y >> 8);
        const int c2 = (int)(char)(rv.y >> 16);
        const int c3 = (int)(char)(rv.y >> 24);
        acc.x = fmaf(wv, (float)c0, acc.x);
        acc.y = fmaf(wv, (float)c1, acc.y);
        acc.z = fmaf(wv, (float)c2, acc.z);
        acc.w = fmaf(wv, (float)c3, acc.w);
    };

    if (T > 0) {
        const int base = B + g;
        // all src loads issued up front (independent)
        const int s0 = src[min(base, dcap)];
        int s1 = 0, s2 = 0, s3 = 0;
        if (T > 1) s1 = src[min(base + 8,  dcap)];
        if (T > 2) s2 = src[min(base + 16, dcap)];
        if (T > 3) s3 = src[min(base + 24, dcap)];
        // row + scale gathers issued together (independent chains)
        uint2 r0 = {0, 0}, r1 = {0, 0}, r2 = {0, 0}, r3 = {0, 0};
        unsigned x0 = 0, x1 = 0, x2 = 0, x3 = 0;
        r0 = ROW[s0 * 8 + c];               x0 = SC[s0];
        if (T > 1) { r1 = ROW[s1 * 8 + c];  x1 = SC[s1]; }
        if (T > 2) { r2 = ROW[s2 * 8 + c];  x2 = SC[s2]; }
        if (T > 3) { r3 = ROW[s3 * 8 + c];  x3 = SC[s3]; }

        step(r0, x0, 0);
        if (T > 1) step(r1, x1, 1);
        if (T > 2) step(r2, x2, 2);
        if (T > 3) step(r3, x3, 3);

        // rare tail (deg > 32): serial, correctness path
        for (int t = 4; t < T; ++t) {
            const int sx = src[min(B + t * 8 + g, dcap)];
            step(ROW[sx * 8 + c], SC[sx], t);
        }
    }

    // per-node reduction: l over all slots; acc folded to 4 slot-pair partials
    l     += __shfl_xor(l, 8);
    acc.x += __shfl_xor(acc.x, 8);
    acc.y += __shfl_xor(acc.y, 8);
    acc.z += __shfl_xor(acc.z, 8);
    acc.w += __shfl_xor(acc.w, 8);
    l += __shfl_xor(l, 16);
    l += __shfl_xor(l, 32);

    const float inv = (deg > 0) ? (1.0f / l) : 0.0f;
    h2 o01, o23;
    o01.x = (_Float16)(acc.x * inv);  o01.y = (_Float16)(acc.y * inv);
    o23.x = (_Float16)(acc.z * inv);  o23.y = (_Float16)(acc.w * inv);

    if ((g & 1) == 0) {                  // even slots hold pair sums
        unsigned* part32 = (unsigned*)s_part;
        const int off = w * 68 + (g >> 1) * 16 + c * 2;   // uint32 units
        part32[off]     = as_u32(o01);
        part32[off + 1] = as_u32(o23);
    }

    __syncthreads();

    // wave 0: projection for the block's 8 nodes via 16x16x32 f16 MFMA
    // (A rows 8..15 are zero; C rows 8..15 discarded)
    if (w == 0) {
        const int quad = lane >> 4;   // 0..3
        const int col  = lane & 15;

        union BF { h8 v; _Float16 u[8]; };
        BF bf0, bf1;
#pragma unroll
        for (int j2 = 0; j2 < 8; ++j2) {
            bf0.u[j2] = (_Float16)Wo[(quad * 8 + j2) * OUT_DIM + col];
            bf1.u[j2] = (_Float16)Wo[(quad * 8 + j2) * OUT_DIM + 16 + col];
        }
        const float bias0 = bo[col];
        const float bias1 = bo[16 + col];

        union AF { uint4 u; h8 v; };
        f32x4 C0 = {bias0, bias0, bias0, bias0};
        f32x4 C1 = {bias1, bias1, bias1, bias1};
#pragma unroll
        for (int cc = 0; cc < 4; ++cc) {
            AF a;
            a.u = s_part[col * 17 + cc * 4 + quad];      // ds_read_b128
            C0 = __builtin_amdgcn_mfma_f32_16x16x32_f16(a.v, bf0.v, C0, 0, 0, 0);
            C1 = __builtin_amdgcn_mfma_f32_16x16x32_f16(a.v, bf1.v, C1, 0, 0, 0);
        }
        // C/D layout: col = lane&15, row = quad*4 + reg (verified mapping)
        if (quad < 2) {                 // only rows 0..7 are real nodes
#pragma unroll
            for (int r = 0; r < 4; ++r) {
                const int n2 = n_blk + quad * 4 + r;
                if (n2 < N) {
                    out[n2 * OUT_DIM + col]      = C0[r];
                    out[n2 * OUT_DIM + 16 + col] = C1[r];
                }
            }
        }
    }
}

// ---- fallback (R4-proven fp32 path, used only if ws too small) ------------
__global__ __launch_bounds__(256) void gat_node_f32_kernel(
    const float* __restrict__ X, const float* __restrict__ Km,
    const float* __restrict__ Vm, const float* __restrict__ Wo,
    const float* __restrict__ bo, const int* __restrict__ src,
    const int* __restrict__ row_ptr, float* __restrict__ out, int N) {
    const int tid  = threadIdx.x;
    const int wave = tid >> 6;
    const int lane = tid & 63;
    const int g    = lane >> 3;
    const int c    = lane & 7;
    const int j    = lane & 31;
    const int half = lane >> 5;
    const int n = blockIdx.x * 4 + wave;
    if (n >= N) return;
    const int begin = row_ptr[n];
    const int end   = row_ptr[n + 1];
    const float4* X4 = (const float4*)X;
    const float4* K4 = (const float4*)Km;
    const float4* V4 = (const float4*)Vm;
    const float4 q4 = X4[n * 8 + c];
    float  l   = 0.0f;
    float4 acc = make_float4(0.0f, 0.0f, 0.0f, 0.0f);
    for (int e0 = begin; e0 < end; e0 += 16) {
        const int  ea = e0 + g;
        const int  eb = ea + 8;
        const bool va = ea < end;
        const bool vb = eb < end;
        const int sa = src[min(ea, end - 1)];
        const int sb = src[min(eb, end - 1)];
        const float4 ka  = K4[sa * 8 + c];
        const float4 kb  = K4[sb * 8 + c];
        const float4 vva = V4[sa * 8 + c];
        const float4 vvb = V4[sb * 8 + c];
        float pa = fmaf(ka.x, q4.x, fmaf(ka.y, q4.y, fmaf(ka.z, q4.z, ka.w * q4.w)));
        float pb = fmaf(kb.x, q4.x, fmaf(kb.y, q4.y, fmaf(kb.z, q4.z, kb.w * q4.w)));
        pa += __shfl_xor(pa, 1);  pb += __shfl_xor(pb, 1);
        pa += __shfl_xor(pa, 2);  pb += __shfl_xor(pb, 2);
        pa += __shfl_xor(pa, 4);  pb += __shfl_xor(pb, 4);
        const float wa = va ? __expf(pa * 0.03125f) : 0.0f;
        const float wb = vb ? __expf(pb * 0.03125f) : 0.0f;
        l += wa + wb;
        acc.x = fmaf(wa, vva.x, acc.x);  acc.y = fmaf(wa, vva.y, acc.y);
        acc.z = fmaf(wa, vva.z, acc.z);  acc.w = fmaf(wa, vva.w, acc.w);
        acc.x = fmaf(wb, vvb.x, acc.x);  acc.y = fmaf(wb, vvb.y, acc.y);
        acc.z = fmaf(wb, vvb.z, acc.z);  acc.w = fmaf(wb, vvb.w, acc.w);
    }
#pragma unroll
    for (int m = 8; m <= 32; m <<= 1) {
        l     += __shfl_xor(l, m);
        acc.x += __shfl_xor(acc.x, m);
        acc.y += __shfl_xor(acc.y, m);
        acc.z += __shfl_xor(acc.z, m);
        acc.w += __shfl_xor(acc.w, m);
    }
    const float inv = (end > begin) ? (1.0f / l) : 0.0f;
    float ag[4] = {acc.x, acc.y, acc.z, acc.w};
    float s = 0.0f;
#pragma unroll
    for (int k = 0; k < 32; ++k) {
        const float a = __int_as_float(
            __builtin_amdgcn_readlane(__float_as_int(ag[k & 3]), k >> 2));
        s = fmaf(a, Wo[k * OUT_DIM + j], s);
    }
    if (half == 0) {
        out[n * OUT_DIM + j] = fmaf(s, inv, bo[j]);
    }
}

extern "C" void kernel_launch(void* const* d_in, const int* in_sizes, int n_in,
                              void* d_out, int out_size, void* d_ws, size_t ws_size,
                              hipStream_t stream) {
    const float* X  = (const float*)d_in[0];
    const float* Km = (const float*)d_in[1];
    const float* Vm = (const float*)d_in[2];
    const float* Wo = (const float*)d_in[3];
    const float* bo = (const float*)d_in[4];
    const int* src  = (const int*)d_in[5];
    const int* dst  = (const int*)d_in[6];

    const int N = in_sizes[0] / DK;
    const int E = in_sizes[5];

    int* row_ptr = (int*)d_ws;                              // (N+1) ints
    const size_t row_off = (((size_t)(N + 1) * 4) + 127) & ~(size_t)127;
    const size_t sc_off  = ((row_off + (size_t)N * 64) + 127) & ~(size_t)127;
    uint2*    ROW = (uint2*)((char*)d_ws + row_off);        // N x 64 B
    unsigned* SCt = (unsigned*)((char*)d_ws + sc_off);      // N dwords
    const size_t need = sc_off + (size_t)N * 4;
    float* out = (float*)d_out;

    const int tb = 256;

    if (ws_size >= need) {
        const int nE4   = (E + 3) / 4;       // 4 edges per thread (dst scan)
        const int prep_n = (nE4 > N) ? nE4 : N;
        prep_kernel<<<(prep_n + tb - 1) / tb, tb, 0, stream>>>(
            dst, (const float4*)Km, (const float4*)Vm, E, N,
            row_ptr, ROW, SCt);
        const int grid = (N + 7) / 8;       // 8 nodes per block, 1 per wave
        gat_fused_kernel<<<grid, 512, 0, stream>>>(X, ROW, SCt, Wo, bo,
                                                   src, row_ptr, out, N);
    } else {
        build_row_ptr_kernel<<<(E + tb - 1) / tb, tb, 0, stream>>>(dst, E, N, row_ptr);
        const int grid = (N + 3) / 4;
        gat_node_f32_kernel<<<grid, 256, 0, stream>>>(X, Km, Vm, Wo, bo,
                                                      src, row_ptr, out, N);
    }
}

// Round 6
// 145.679 us; speedup vs baseline: 1.0343x; 1.0050x over previous
//
#include <hip/hip_runtime.h>
#include <math.h>

#define DK 32
#define OUT_DIM 32

typedef float    f32x4 __attribute__((ext_vector_type(4)));
typedef _Float16 h2    __attribute__((ext_vector_type(2)));
typedef _Float16 h8    __attribute__((ext_vector_type(8)));

#if __has_builtin(__builtin_amdgcn_exp2f)
#define EXP2F(x) __builtin_amdgcn_exp2f(x)
#else
#define EXP2F(x) exp2f(x)
#endif

__device__ __forceinline__ h2 as_h2(unsigned u) {
    union { unsigned u; h2 h; } v; v.u = u; return v.h;
}
__device__ __forceinline__ unsigned as_u32(h2 h) {
    union { unsigned u; h2 h; } v; v.h = h; return v.u;
}

// ---- int8 quantizer (per-node scale) --------------------------------------
__device__ __forceinline__ unsigned q8b(float x, float r) {
    int i = (int)rintf(x * r);
    i = min(127, max(-127, i));
    return (unsigned)(i & 255);
}
__device__ __forceinline__ unsigned pack8x4(float4 f, float r) {
    return q8b(f.x, r) | (q8b(f.y, r) << 8) |
           (q8b(f.z, r) << 16) | (q8b(f.w, r) << 24);
}

// R16-proven prep: ONE 64 B int8 row per node holding BOTH K and V, per-node
// f16 dequant scales in a 400 KB side table. Row layout: 8 x uint2 chunks;
// chunk c = {K[4c..4c+3] int8, V[4c..4c+3] int8}. dst scan int4-vectorized.
__global__ void prep_kernel(const int* __restrict__ dst,
                            const float4* __restrict__ K4,
                            const float4* __restrict__ V4,
                            int E, int N,
                            int* __restrict__ row_ptr,
                            uint2* __restrict__ ROW,
                            unsigned* __restrict__ SC) {
    const int t  = blockIdx.x * blockDim.x + threadIdx.x;
    const int e0 = t * 4;
    if (e0 < E) {
        int cur[4];
        if (e0 + 4 <= E) {
            const int4 dd = *(const int4*)(dst + e0);
            cur[0] = dd.x; cur[1] = dd.y; cur[2] = dd.z; cur[3] = dd.w;
        } else {
#pragma unroll
            for (int k = 0; k < 4; ++k)
                cur[k] = (e0 + k < E) ? dst[e0 + k] : 0;
        }
        int prev = (e0 == 0) ? -1 : dst[e0 - 1];
#pragma unroll
        for (int k = 0; k < 4; ++k) {
            const int ee = e0 + k;
            if (ee < E) {
                for (int j = prev + 1; j <= cur[k]; ++j) row_ptr[j] = ee;
                if (ee == E - 1)
                    for (int j = cur[k] + 1; j <= N; ++j) row_ptr[j] = E;
                prev = cur[k];
            }
        }
    }
    if (t < N) {
        float4 kf[8], vf[8];
#pragma unroll
        for (int u = 0; u < 8; ++u) { kf[u] = K4[t * 8 + u]; vf[u] = V4[t * 8 + u]; }
        float mk = 0.0f, mv = 0.0f;
#pragma unroll
        for (int u = 0; u < 8; ++u) {
            mk = fmaxf(mk, fmaxf(fmaxf(fabsf(kf[u].x), fabsf(kf[u].y)),
                                 fmaxf(fabsf(kf[u].z), fabsf(kf[u].w))));
            mv = fmaxf(mv, fmaxf(fmaxf(fabsf(vf[u].x), fabsf(vf[u].y)),
                                 fmaxf(fabsf(vf[u].z), fabsf(vf[u].w))));
        }
        const float rk = (mk > 0.0f) ? 127.0f / mk : 0.0f;
        const float rv = (mv > 0.0f) ? 127.0f / mv : 0.0f;
        uint4* o4 = (uint4*)(ROW + t * 8);
#pragma unroll
        for (int u2 = 0; u2 < 4; ++u2) {
            uint4 o;
            o.x = pack8x4(kf[2 * u2],     rk);
            o.y = pack8x4(vf[2 * u2],     rv);
            o.z = pack8x4(kf[2 * u2 + 1], rk);
            o.w = pack8x4(vf[2 * u2 + 1], rv);
            o4[u2] = o;
        }
        h2 s;
        s.x = (_Float16)(mk * (1.0f / 127.0f));   // K dequant scale
        s.y = (_Float16)(mv * (1.0f / 127.0f));   // V dequant scale
        SC[t] = as_u32(s);
    }
}

// Fallback-path row_ptr builder (ws too small for packed tables).
__global__ void build_row_ptr_kernel(const int* __restrict__ dst, int E, int N,
                                     int* __restrict__ row_ptr) {
    int e = blockIdx.x * blockDim.x + threadIdx.x;
    if (e >= E) return;
    int cur  = dst[e];
    int prev = (e == 0) ? -1 : dst[e - 1];
    for (int j = prev + 1; j <= cur; ++j) row_ptr[j] = e;
    if (e == E - 1) {
        for (int j = cur + 1; j <= N; ++j) row_ptr[j] = E;
    }
}

// R17 = R16 + REGISTER BUDGET FIX.
// Post-mortem R16: FETCH dropped 86->68 MB, dur unchanged at 49 us, and
// VGPR_Count = 20. With 20 VGPRs the emitted code CANNOT hold 4 src + 4 row
// + 4 scale gather results concurrently -> compiler reuses result regs and
// inserts waitcnts between gathers, serializing the "parallel" chains into
// T+1 sequential ~600 cy round-trips. That register starvation (default
// max-occupancy scheduling under __launch_bounds__(512)) is the 44-49 us
// floor across R11-R16: R11/R12 (VGPR=44) = 44 us beat R14/R16 (VGPR=20) =
// 49 us despite "better" structure. Fix: __launch_bounds__(512, 2) -> VGPR
// cap 128, scheduler optimizes ILP, all gather chains genuinely in flight.
// Src loads made unconditional (clamped, streaming-hot) so each T-guarded
// row gather is 1-deep with its address ready. Numerics identical to R16.
__global__ __launch_bounds__(512, 2) void gat_fused_kernel(
    const float* __restrict__ X, const uint2* __restrict__ ROW,
    const unsigned* __restrict__ SC,
    const float* __restrict__ Wo, const float* __restrict__ bo,
    const int* __restrict__ src, const int* __restrict__ row_ptr,
    float* __restrict__ out, int N) {

    __shared__ uint4 s_part[16 * 17];   // 16-row A-tile, row stride 17 (pad)

    const int tid  = threadIdx.x;
    const int w    = tid >> 6;    // wave 0..7 = node offset in block
    const int lane = tid & 63;
    const int g    = lane >> 3;   // edge slot 0..7
    const int c    = lane & 7;    // dim chunk 0..7

    const int n_blk = blockIdx.x * 8;
    const int n     = n_blk + w;

    // zero A-tile rows 8..15 (read by MFMA, never stored)
    if (tid < 136) {
        uint4 z; z.x = 0; z.y = 0; z.z = 0; z.w = 0;
        s_part[136 + tid] = z;
    }

    // wave-uniform segment bounds (readfirstlane -> SALU)
    const int B    = __builtin_amdgcn_readfirstlane(row_ptr[min(n, N)]);
    const int En   = __builtin_amdgcn_readfirstlane(row_ptr[min(n + 1, N)]);
    const int deg  = En - B;
    const int dcap = max(En - 1, 0);
    const int T    = (deg + 7) >> 3;

    const float scale = 0.03125f * 1.44269504f;  // 1/dk * log2(e) for exp2
    float4 qf = ((const float4*)X)[min(n, N - 1) * 8 + c];
    qf.x *= scale; qf.y *= scale; qf.z *= scale; qf.w *= scale;

    float l = 0.0f;
    f32x4 acc = {0.0f, 0.0f, 0.0f, 0.0f};

    auto step = [&](uint2 rv, unsigned sc, int t) {
        const h2 sch = as_h2(sc);
        const float sK = (float)sch.x;
        const float sV = (float)sch.y;
        const int b0 = (int)(char)(rv.x);
        const int b1 = (int)(char)(rv.x >> 8);
        const int b2 = (int)(char)(rv.x >> 16);
        const int b3 = (int)(char)(rv.x >> 24);
        float p = fmaf(qf.x, (float)b0, fmaf(qf.y, (float)b1,
                  fmaf(qf.z, (float)b2, qf.w * (float)b3)));
        p += __shfl_xor(p, 1);
        p += __shfl_xor(p, 2);
        p += __shfl_xor(p, 4);
        p *= sK;
        const float wt = (t * 8 + g < deg) ? EXP2F(p) : 0.0f;
        l += wt;
        const float wv = wt * sV;
        const int c0 = (int)(char)(rv.y);
        const int c1 = (int)(char)(rv.y >> 8);
        const int c2 = (int)(char)(rv.y >> 16);
        const int c3 = (int)(char)(rv.y >> 24);
        acc.x = fmaf(wv, (float)c0, acc.x);
        acc.y = fmaf(wv, (float)c1, acc.y);
        acc.z = fmaf(wv, (float)c2, acc.z);
        acc.w = fmaf(wv, (float)c3, acc.w);
    };

    if (T > 0) {
        const int base = B + g;
        // ALL 4 src loads unconditional (clamped; src is a hot stream) --
        // 4 independent dword loads, no branches, addresses ready for rows.
        const int s0 = src[min(base,      dcap)];
        const int s1 = src[min(base + 8,  dcap)];
        const int s2 = src[min(base + 16, dcap)];
        const int s3 = src[min(base + 24, dcap)];
        // row + scale gathers: 4 independent 1-deep chains, issued together
        uint2 r0 = {0, 0}, r1 = {0, 0}, r2 = {0, 0}, r3 = {0, 0};
        unsigned x0 = 0, x1 = 0, x2 = 0, x3 = 0;
        r0 = ROW[s0 * 8 + c];               x0 = SC[s0];
        if (T > 1) { r1 = ROW[s1 * 8 + c];  x1 = SC[s1]; }
        if (T > 2) { r2 = ROW[s2 * 8 + c];  x2 = SC[s2]; }
        if (T > 3) { r3 = ROW[s3 * 8 + c];  x3 = SC[s3]; }

        step(r0, x0, 0);
        if (T > 1) step(r1, x1, 1);
        if (T > 2) step(r2, x2, 2);
        if (T > 3) step(r3, x3, 3);

        // rare tail (deg > 32): serial, correctness path
        for (int t = 4; t < T; ++t) {
            const int sx = src[min(B + t * 8 + g, dcap)];
            step(ROW[sx * 8 + c], SC[sx], t);
        }
    }

    // per-node reduction: l over all slots; acc folded to 4 slot-pair partials
    l     += __shfl_xor(l, 8);
    acc.x += __shfl_xor(acc.x, 8);
    acc.y += __shfl_xor(acc.y, 8);
    acc.z += __shfl_xor(acc.z, 8);
    acc.w += __shfl_xor(acc.w, 8);
    l += __shfl_xor(l, 16);
    l += __shfl_xor(l, 32);

    const float inv = (deg > 0) ? (1.0f / l) : 0.0f;
    h2 o01, o23;
    o01.x = (_Float16)(acc.x * inv);  o01.y = (_Float16)(acc.y * inv);
    o23.x = (_Float16)(acc.z * inv);  o23.y = (_Float16)(acc.w * inv);

    if ((g & 1) == 0) {                  // even slots hold pair sums
        unsigned* part32 = (unsigned*)s_part;
        const int off = w * 68 + (g >> 1) * 16 + c * 2;   // uint32 units
        part32[off]     = as_u32(o01);
        part32[off + 1] = as_u32(o23);
    }

    __syncthreads();

    // wave 0: projection for the block's 8 nodes via 16x16x32 f16 MFMA
    // (A rows 8..15 are zero; C rows 8..15 discarded)
    if (w == 0) {
        const int quad = lane >> 4;   // 0..3
        const int col  = lane & 15;

        union BF { h8 v; _Float16 u[8]; };
        BF bf0, bf1;
#pragma unroll
        for (int j2 = 0; j2 < 8; ++j2) {
            bf0.u[j2] = (_Float16)Wo[(quad * 8 + j2) * OUT_DIM + col];
            bf1.u[j2] = (_Float16)Wo[(quad * 8 + j2) * OUT_DIM + 16 + col];
        }
        const float bias0 = bo[col];
        const float bias1 = bo[16 + col];

        union AF { uint4 u; h8 v; };
        f32x4 C0 = {bias0, bias0, bias0, bias0};
        f32x4 C1 = {bias1, bias1, bias1, bias1};
#pragma unroll
        for (int cc = 0; cc < 4; ++cc) {
            AF a;
            a.u = s_part[col * 17 + cc * 4 + quad];      // ds_read_b128
            C0 = __builtin_amdgcn_mfma_f32_16x16x32_f16(a.v, bf0.v, C0, 0, 0, 0);
            C1 = __builtin_amdgcn_mfma_f32_16x16x32_f16(a.v, bf1.v, C1, 0, 0, 0);
        }
        // C/D layout: col = lane&15, row = quad*4 + reg (verified mapping)
        if (quad < 2) {                 // only rows 0..7 are real nodes
#pragma unroll
            for (int r = 0; r < 4; ++r) {
                const int n2 = n_blk + quad * 4 + r;
                if (n2 < N) {
                    out[n2 * OUT_DIM + col]      = C0[r];
                    out[n2 * OUT_DIM + 16 + col] = C1[r];
                }
            }
        }
    }
}

// ---- fallback (R4-proven fp32 path, used only if ws too small) ------------
__global__ __launch_bounds__(256) void gat_node_f32_kernel(
    const float* __restrict__ X, const float* __restrict__ Km,
    const float* __restrict__ Vm, const float* __restrict__ Wo,
    const float* __restrict__ bo, const int* __restrict__ src,
    const int* __restrict__ row_ptr, float* __restrict__ out, int N) {
    const int tid  = threadIdx.x;
    const int wave = tid >> 6;
    const int lane = tid & 63;
    const int g    = lane >> 3;
    const int c    = lane & 7;
    const int j    = lane & 31;
    const int half = lane >> 5;
    const int n = blockIdx.x * 4 + wave;
    if (n >= N) return;
    const int begin = row_ptr[n];
    const int end   = row_ptr[n + 1];
    const float4* X4 = (const float4*)X;
    const float4* K4 = (const float4*)Km;
    const float4* V4 = (const float4*)Vm;
    const float4 q4 = X4[n * 8 + c];
    float  l   = 0.0f;
    float4 acc = make_float4(0.0f, 0.0f, 0.0f, 0.0f);
    for (int e0 = begin; e0 < end; e0 += 16) {
        const int  ea = e0 + g;
        const int  eb = ea + 8;
        const bool va = ea < end;
        const bool vb = eb < end;
        const int sa = src[min(ea, end - 1)];
        const int sb = src[min(eb, end - 1)];
        const float4 ka  = K4[sa * 8 + c];
        const float4 kb  = K4[sb * 8 + c];
        const float4 vva = V4[sa * 8 + c];
        const float4 vvb = V4[sb * 8 + c];
        float pa = fmaf(ka.x, q4.x, fmaf(ka.y, q4.y, fmaf(ka.z, q4.z, ka.w * q4.w)));
        float pb = fmaf(kb.x, q4.x, fmaf(kb.y, q4.y, fmaf(kb.z, q4.z, kb.w * q4.w)));
        pa += __shfl_xor(pa, 1);  pb += __shfl_xor(pb, 1);
        pa += __shfl_xor(pa, 2);  pb += __shfl_xor(pb, 2);
        pa += __shfl_xor(pa, 4);  pb += __shfl_xor(pb, 4);
        const float wa = va ? __expf(pa * 0.03125f) : 0.0f;
        const float wb = vb ? __expf(pb * 0.03125f) : 0.0f;
        l += wa + wb;
        acc.x = fmaf(wa, vva.x, acc.x);  acc.y = fmaf(wa, vva.y, acc.y);
        acc.z = fmaf(wa, vva.z, acc.z);  acc.w = fmaf(wa, vva.w, acc.w);
        acc.x = fmaf(wb, vvb.x, acc.x);  acc.y = fmaf(wb, vvb.y, acc.y);
        acc.z = fmaf(wb, vvb.z, acc.z);  acc.w = fmaf(wb, vvb.w, acc.w);
    }
#pragma unroll
    for (int m = 8; m <= 32; m <<= 1) {
        l     += __shfl_xor(l, m);
        acc.x += __shfl_xor(acc.x, m);
        acc.y += __shfl_xor(acc.y, m);
        acc.z += __shfl_xor(acc.z, m);
        acc.w += __shfl_xor(acc.w, m);
    }
    const float inv = (end > begin) ? (1.0f / l) : 0.0f;
    float ag[4] = {acc.x, acc.y, acc.z, acc.w};
    float s = 0.0f;
#pragma unroll
    for (int k = 0; k < 32; ++k) {
        const float a = __int_as_float(
            __builtin_amdgcn_readlane(__float_as_int(ag[k & 3]), k >> 2));
        s = fmaf(a, Wo[k * OUT_DIM + j], s);
    }
    if (half == 0) {
        out[n * OUT_DIM + j] = fmaf(s, inv, bo[j]);
    }
}

extern "C" void kernel_launch(void* const* d_in, const int* in_sizes, int n_in,
                              void* d_out, int out_size, void* d_ws, size_t ws_size,
                              hipStream_t stream) {
    const float* X  = (const float*)d_in[0];
    const float* Km = (const float*)d_in[1];
    const float* Vm = (const float*)d_in[2];
    const float* Wo = (const float*)d_in[3];
    const float* bo = (const float*)d_in[4];
    const int* src  = (const int*)d_in[5];
    const int* dst  = (const int*)d_in[6];

    const int N = in_sizes[0] / DK;
    const int E = in_sizes[5];

    int* row_ptr = (int*)d_ws;                              // (N+1) ints
    const size_t row_off = (((size_t)(N + 1) * 4) + 127) & ~(size_t)127;
    const size_t sc_off  = ((row_off + (size_t)N * 64) + 127) & ~(size_t)127;
    uint2*    ROW = (uint2*)((char*)d_ws + row_off);        // N x 64 B
    unsigned* SCt = (unsigned*)((char*)d_ws + sc_off);      // N dwords
    const size_t need = sc_off + (size_t)N * 4;
    float* out = (float*)d_out;

    const int tb = 256;

    if (ws_size >= need) {
        const int nE4   = (E + 3) / 4;       // 4 edges per thread (dst scan)
        const int prep_n = (nE4 > N) ? nE4 : N;
        prep_kernel<<<(prep_n + tb - 1) / tb, tb, 0, stream>>>(
            dst, (const float4*)Km, (const float4*)Vm, E, N,
            row_ptr, ROW, SCt);
        const int grid = (N + 7) / 8;       // 8 nodes per block, 1 per wave
        gat_fused_kernel<<<grid, 512, 0, stream>>>(X, ROW, SCt, Wo, bo,
                                                   src, row_ptr, out, N);
    } else {
        build_row_ptr_kernel<<<(E + tb - 1) / tb, tb, 0, stream>>>(dst, E, N, row_ptr);
        const int grid = (N + 3) / 4;
        gat_node_f32_kernel<<<grid, 256, 0, stream>>>(X, Km, Vm, Wo, bo,
                                                      src, row_ptr, out, N);
    }
}

// Round 7
// 144.660 us; speedup vs baseline: 1.0416x; 1.0070x over previous
//
#include <hip/hip_runtime.h>
#include <math.h>

#define DK 32
#define OUT_DIM 32

typedef float    f32x4 __attribute__((ext_vector_type(4)));
typedef _Float16 h2    __attribute__((ext_vector_type(2)));
typedef _Float16 h8    __attribute__((ext_vector_type(8)));

#if __has_builtin(__builtin_amdgcn_exp2f)
#define EXP2F(x) __builtin_amdgcn_exp2f(x)
#else
#define EXP2F(x) exp2f(x)
#endif

__device__ __forceinline__ h2 as_h2(unsigned u) {
    union { unsigned u; h2 h; } v; v.u = u; return v.h;
}
__device__ __forceinline__ unsigned as_u32(h2 h) {
    union { unsigned u; h2 h; } v; v.h = h; return v.u;
}

// ---- int8 quantizer (per-node scale) --------------------------------------
__device__ __forceinline__ unsigned q8b(float x, float r) {
    int i = (int)rintf(x * r);
    i = min(127, max(-127, i));
    return (unsigned)(i & 255);
}
__device__ __forceinline__ unsigned pack8x4(float4 f, float r) {
    return q8b(f.x, r) | (q8b(f.y, r) << 8) |
           (q8b(f.z, r) << 16) | (q8b(f.w, r) << 24);
}

// R16-proven prep: ONE 64 B int8 row per node holding BOTH K and V, per-node
// f16 dequant scales in a 400 KB side table. Row layout: 8 x uint2 chunks;
// chunk c = {K[4c..4c+3] int8, V[4c..4c+3] int8}. dst scan int4-vectorized.
__global__ void prep_kernel(const int* __restrict__ dst,
                            const float4* __restrict__ K4,
                            const float4* __restrict__ V4,
                            int E, int N,
                            int* __restrict__ row_ptr,
                            uint2* __restrict__ ROW,
                            unsigned* __restrict__ SC) {
    const int t  = blockIdx.x * blockDim.x + threadIdx.x;
    const int e0 = t * 4;
    if (e0 < E) {
        int cur[4];
        if (e0 + 4 <= E) {
            const int4 dd = *(const int4*)(dst + e0);
            cur[0] = dd.x; cur[1] = dd.y; cur[2] = dd.z; cur[3] = dd.w;
        } else {
#pragma unroll
            for (int k = 0; k < 4; ++k)
                cur[k] = (e0 + k < E) ? dst[e0 + k] : 0;
        }
        int prev = (e0 == 0) ? -1 : dst[e0 - 1];
#pragma unroll
        for (int k = 0; k < 4; ++k) {
            const int ee = e0 + k;
            if (ee < E) {
                for (int j = prev + 1; j <= cur[k]; ++j) row_ptr[j] = ee;
                if (ee == E - 1)
                    for (int j = cur[k] + 1; j <= N; ++j) row_ptr[j] = E;
                prev = cur[k];
            }
        }
    }
    if (t < N) {
        float4 kf[8], vf[8];
#pragma unroll
        for (int u = 0; u < 8; ++u) { kf[u] = K4[t * 8 + u]; vf[u] = V4[t * 8 + u]; }
        float mk = 0.0f, mv = 0.0f;
#pragma unroll
        for (int u = 0; u < 8; ++u) {
            mk = fmaxf(mk, fmaxf(fmaxf(fabsf(kf[u].x), fabsf(kf[u].y)),
                                 fmaxf(fabsf(kf[u].z), fabsf(kf[u].w))));
            mv = fmaxf(mv, fmaxf(fmaxf(fabsf(vf[u].x), fabsf(vf[u].y)),
                                 fmaxf(fabsf(vf[u].z), fabsf(vf[u].w))));
        }
        const float rk = (mk > 0.0f) ? 127.0f / mk : 0.0f;
        const float rv = (mv > 0.0f) ? 127.0f / mv : 0.0f;
        uint4* o4 = (uint4*)(ROW + t * 8);
#pragma unroll
        for (int u2 = 0; u2 < 4; ++u2) {
            uint4 o;
            o.x = pack8x4(kf[2 * u2],     rk);
            o.y = pack8x4(vf[2 * u2],     rv);
            o.z = pack8x4(kf[2 * u2 + 1], rk);
            o.w = pack8x4(vf[2 * u2 + 1], rv);
            o4[u2] = o;
        }
        h2 s;
        s.x = (_Float16)(mk * (1.0f / 127.0f));   // K dequant scale
        s.y = (_Float16)(mv * (1.0f / 127.0f));   // V dequant scale
        SC[t] = as_u32(s);
    }
}

// Fallback-path row_ptr builder (ws too small for packed tables).
__global__ void build_row_ptr_kernel(const int* __restrict__ dst, int E, int N,
                                     int* __restrict__ row_ptr) {
    int e = blockIdx.x * blockDim.x + threadIdx.x;
    if (e >= E) return;
    int cur  = dst[e];
    int prev = (e == 0) ? -1 : dst[e - 1];
    for (int j = prev + 1; j <= cur; ++j) row_ptr[j] = e;
    if (e == E - 1) {
        for (int j = cur + 1; j <= N; ++j) row_ptr[j] = E;
    }
}

// R18 = R16 numerics + ISA-LEVEL ILP FENCES.
// Post-mortem R17: VGPR_Count stayed 20 -- __launch_bounds__ only CAPS
// registers, it doesn't make the scheduler keep 12 gather results live, so
// the emitted code still serialized the chains (issue->wait->consume, x4,
// ~700 cy each; per-wave critical path ~6.1k cy vs ~1.2k cy of issue).
// Fix: empty inline-asm with "+v" operand constraints. The asm READS the
// loaded values, so (a) every load must be ISSUED before the fence (can't
// be sunk past it), (b) one s_waitcnt covers the whole flight, (c) the
// register allocator is forced to keep all results live -> VGPR_Count is
// the built-in verification (must rise to >=40, else fence failed).
// Numerics bit-identical to R16/R17 (absmax 0.01220703).
__global__ __launch_bounds__(512, 2) void gat_fused_kernel(
    const float* __restrict__ X, const uint2* __restrict__ ROW,
    const unsigned* __restrict__ SC,
    const float* __restrict__ Wo, const float* __restrict__ bo,
    const int* __restrict__ src, const int* __restrict__ row_ptr,
    float* __restrict__ out, int N) {

    __shared__ uint4 s_part[16 * 17];   // 16-row A-tile, row stride 17 (pad)

    const int tid  = threadIdx.x;
    const int w    = tid >> 6;    // wave 0..7 = node offset in block
    const int lane = tid & 63;
    const int g    = lane >> 3;   // edge slot 0..7
    const int c    = lane & 7;    // dim chunk 0..7

    const int n_blk = blockIdx.x * 8;
    const int n     = n_blk + w;

    // zero A-tile rows 8..15 (read by MFMA, never stored)
    if (tid < 136) {
        uint4 z; z.x = 0; z.y = 0; z.z = 0; z.w = 0;
        s_part[136 + tid] = z;
    }

    // wave-uniform segment bounds (readfirstlane -> SALU)
    const int B    = __builtin_amdgcn_readfirstlane(row_ptr[min(n, N)]);
    const int En   = __builtin_amdgcn_readfirstlane(row_ptr[min(n + 1, N)]);
    const int deg  = En - B;
    const int dcap = max(En - 1, 0);
    const int T    = (deg + 7) >> 3;

    const float scale = 0.03125f * 1.44269504f;  // 1/dk * log2(e) for exp2
    float4 qf = ((const float4*)X)[min(n, N - 1) * 8 + c];
    qf.x *= scale; qf.y *= scale; qf.z *= scale; qf.w *= scale;

    float l = 0.0f;
    f32x4 acc = {0.0f, 0.0f, 0.0f, 0.0f};

    auto step = [&](uint2 rv, unsigned sc, int t) {
        const h2 sch = as_h2(sc);
        const float sK = (float)sch.x;
        const float sV = (float)sch.y;
        const int b0 = (int)(char)(rv.x);
        const int b1 = (int)(char)(rv.x >> 8);
        const int b2 = (int)(char)(rv.x >> 16);
        const int b3 = (int)(char)(rv.x >> 24);
        float p = fmaf(qf.x, (float)b0, fmaf(qf.y, (float)b1,
                  fmaf(qf.z, (float)b2, qf.w * (float)b3)));
        p += __shfl_xor(p, 1);
        p += __shfl_xor(p, 2);
        p += __shfl_xor(p, 4);
        p *= sK;
        const float wt = (t * 8 + g < deg) ? EXP2F(p) : 0.0f;
        l += wt;
        const float wv = wt * sV;
        const int c0 = (int)(char)(rv.y);
        const int c1 = (int)(char)(rv.y >> 8);
        const int c2 = (int)(char)(rv.y >> 16);
        const int c3 = (int)(char)(rv.y >> 24);
        acc.x = fmaf(wv, (float)c0, acc.x);
        acc.y = fmaf(wv, (float)c1, acc.y);
        acc.z = fmaf(wv, (float)c2, acc.z);
        acc.w = fmaf(wv, (float)c3, acc.w);
    };

    if (T > 0) {
        const int base = B + g;
        // 4 unconditional clamped src loads (hot stream), issued together.
        int s0 = src[min(base,      dcap)];
        int s1 = src[min(base + 8,  dcap)];
        int s2 = src[min(base + 16, dcap)];
        int s3 = src[min(base + 24, dcap)];
        // ILP fence: all 4 src loads issued+complete here as one flight.
        asm volatile("" : "+v"(s0), "+v"(s1), "+v"(s2), "+v"(s3));

        // row + scale gathers (guarded -> no wasted line-touches)
        uint2 r0 = {0, 0}, r1 = {0, 0}, r2 = {0, 0}, r3 = {0, 0};
        unsigned x0 = 0, x1 = 0, x2 = 0, x3 = 0;
        r0 = ROW[s0 * 8 + c];               x0 = SC[s0];
        if (T > 1) { r1 = ROW[s1 * 8 + c];  x1 = SC[s1]; }
        if (T > 2) { r2 = ROW[s2 * 8 + c];  x2 = SC[s2]; }
        if (T > 3) { r3 = ROW[s3 * 8 + c];  x3 = SC[s3]; }
        // ILP fence: all 12 gather dwords live simultaneously; one waitcnt
        // covers the whole flight instead of one per chain.
        asm volatile("" : "+v"(r0.x), "+v"(r0.y), "+v"(r1.x), "+v"(r1.y),
                          "+v"(r2.x), "+v"(r2.y), "+v"(r3.x), "+v"(r3.y),
                          "+v"(x0), "+v"(x1), "+v"(x2), "+v"(x3));

        step(r0, x0, 0);
        if (T > 1) step(r1, x1, 1);
        if (T > 2) step(r2, x2, 2);
        if (T > 3) step(r3, x3, 3);

        // rare tail (deg > 32): serial, correctness path
        for (int t = 4; t < T; ++t) {
            const int sx = src[min(B + t * 8 + g, dcap)];
            step(ROW[sx * 8 + c], SC[sx], t);
        }
    }

    // per-node reduction: l over all slots; acc folded to 4 slot-pair partials
    l     += __shfl_xor(l, 8);
    acc.x += __shfl_xor(acc.x, 8);
    acc.y += __shfl_xor(acc.y, 8);
    acc.z += __shfl_xor(acc.z, 8);
    acc.w += __shfl_xor(acc.w, 8);
    l += __shfl_xor(l, 16);
    l += __shfl_xor(l, 32);

    const float inv = (deg > 0) ? (1.0f / l) : 0.0f;
    h2 o01, o23;
    o01.x = (_Float16)(acc.x * inv);  o01.y = (_Float16)(acc.y * inv);
    o23.x = (_Float16)(acc.z * inv);  o23.y = (_Float16)(acc.w * inv);

    if ((g & 1) == 0) {                  // even slots hold pair sums
        unsigned* part32 = (unsigned*)s_part;
        const int off = w * 68 + (g >> 1) * 16 + c * 2;   // uint32 units
        part32[off]     = as_u32(o01);
        part32[off + 1] = as_u32(o23);
    }

    __syncthreads();

    // wave 0: projection for the block's 8 nodes via 16x16x32 f16 MFMA
    // (A rows 8..15 are zero; C rows 8..15 discarded)
    if (w == 0) {
        const int quad = lane >> 4;   // 0..3
        const int col  = lane & 15;

        union BF { h8 v; _Float16 u[8]; };
        BF bf0, bf1;
#pragma unroll
        for (int j2 = 0; j2 < 8; ++j2) {
            bf0.u[j2] = (_Float16)Wo[(quad * 8 + j2) * OUT_DIM + col];
            bf1.u[j2] = (_Float16)Wo[(quad * 8 + j2) * OUT_DIM + 16 + col];
        }
        const float bias0 = bo[col];
        const float bias1 = bo[16 + col];

        union AF { uint4 u; h8 v; };
        f32x4 C0 = {bias0, bias0, bias0, bias0};
        f32x4 C1 = {bias1, bias1, bias1, bias1};
#pragma unroll
        for (int cc = 0; cc < 4; ++cc) {
            AF a;
            a.u = s_part[col * 17 + cc * 4 + quad];      // ds_read_b128
            C0 = __builtin_amdgcn_mfma_f32_16x16x32_f16(a.v, bf0.v, C0, 0, 0, 0);
            C1 = __builtin_amdgcn_mfma_f32_16x16x32_f16(a.v, bf1.v, C1, 0, 0, 0);
        }
        // C/D layout: col = lane&15, row = quad*4 + reg (verified mapping)
        if (quad < 2) {                 // only rows 0..7 are real nodes
#pragma unroll
            for (int r = 0; r < 4; ++r) {
                const int n2 = n_blk + quad * 4 + r;
                if (n2 < N) {
                    out[n2 * OUT_DIM + col]      = C0[r];
                    out[n2 * OUT_DIM + 16 + col] = C1[r];
                }
            }
        }
    }
}

// ---- fallback (R4-proven fp32 path, used only if ws too small) ------------
__global__ __launch_bounds__(256) void gat_node_f32_kernel(
    const float* __restrict__ X, const float* __restrict__ Km,
    const float* __restrict__ Vm, const float* __restrict__ Wo,
    const float* __restrict__ bo, const int* __restrict__ src,
    const int* __restrict__ row_ptr, float* __restrict__ out, int N) {
    const int tid  = threadIdx.x;
    const int wave = tid >> 6;
    const int lane = tid & 63;
    const int g    = lane >> 3;
    const int c    = lane & 7;
    const int j    = lane & 31;
    const int half = lane >> 5;
    const int n = blockIdx.x * 4 + wave;
    if (n >= N) return;
    const int begin = row_ptr[n];
    const int end   = row_ptr[n + 1];
    const float4* X4 = (const float4*)X;
    const float4* K4 = (const float4*)Km;
    const float4* V4 = (const float4*)Vm;
    const float4 q4 = X4[n * 8 + c];
    float  l   = 0.0f;
    float4 acc = make_float4(0.0f, 0.0f, 0.0f, 0.0f);
    for (int e0 = begin; e0 < end; e0 += 16) {
        const int  ea = e0 + g;
        const int  eb = ea + 8;
        const bool va = ea < end;
        const bool vb = eb < end;
        const int sa = src[min(ea, end - 1)];
        const int sb = src[min(eb, end - 1)];
        const float4 ka  = K4[sa * 8 + c];
        const float4 kb  = K4[sb * 8 + c];
        const float4 vva = V4[sa * 8 + c];
        const float4 vvb = V4[sb * 8 + c];
        float pa = fmaf(ka.x, q4.x, fmaf(ka.y, q4.y, fmaf(ka.z, q4.z, ka.w * q4.w)));
        float pb = fmaf(kb.x, q4.x, fmaf(kb.y, q4.y, fmaf(kb.z, q4.z, kb.w * q4.w)));
        pa += __shfl_xor(pa, 1);  pb += __shfl_xor(pb, 1);
        pa += __shfl_xor(pa, 2);  pb += __shfl_xor(pb, 2);
        pa += __shfl_xor(pa, 4);  pb += __shfl_xor(pb, 4);
        const float wa = va ? __expf(pa * 0.03125f) : 0.0f;
        const float wb = vb ? __expf(pb * 0.03125f) : 0.0f;
        l += wa + wb;
        acc.x = fmaf(wa, vva.x, acc.x);  acc.y = fmaf(wa, vva.y, acc.y);
        acc.z = fmaf(wa, vva.z, acc.z);  acc.w = fmaf(wa, vva.w, acc.w);
        acc.x = fmaf(wb, vvb.x, acc.x);  acc.y = fmaf(wb, vvb.y, acc.y);
        acc.z = fmaf(wb, vvb.z, acc.z);  acc.w = fmaf(wb, vvb.w, acc.w);
    }
#pragma unroll
    for (int m = 8; m <= 32; m <<= 1) {
        l     += __shfl_xor(l, m);
        acc.x += __shfl_xor(acc.x, m);
        acc.y += __shfl_xor(acc.y, m);
        acc.z += __shfl_xor(acc.z, m);
        acc.w += __shfl_xor(acc.w, m);
    }
    const float inv = (end > begin) ? (1.0f / l) : 0.0f;
    float ag[4] = {acc.x, acc.y, acc.z, acc.w};
    float s = 0.0f;
#pragma unroll
    for (int k = 0; k < 32; ++k) {
        const float a = __int_as_float(
            __builtin_amdgcn_readlane(__float_as_int(ag[k & 3]), k >> 2));
        s = fmaf(a, Wo[k * OUT_DIM + j], s);
    }
    if (half == 0) {
        out[n * OUT_DIM + j] = fmaf(s, inv, bo[j]);
    }
}

extern "C" void kernel_launch(void* const* d_in, const int* in_sizes, int n_in,
                              void* d_out, int out_size, void* d_ws, size_t ws_size,
                              hipStream_t stream) {
    const float* X  = (const float*)d_in[0];
    const float* Km = (const float*)d_in[1];
    const float* Vm = (const float*)d_in[2];
    const float* Wo = (const float*)d_in[3];
    const float* bo = (const float*)d_in[4];
    const int* src  = (const int*)d_in[5];
    const int* dst  = (const int*)d_in[6];

    const int N = in_sizes[0] / DK;
    const int E = in_sizes[5];

    int* row_ptr = (int*)d_ws;                              // (N+1) ints
    const size_t row_off = (((size_t)(N + 1) * 4) + 127) & ~(size_t)127;
    const size_t sc_off  = ((row_off + (size_t)N * 64) + 127) & ~(size_t)127;
    uint2*    ROW = (uint2*)((char*)d_ws + row_off);        // N x 64 B
    unsigned* SCt = (unsigned*)((char*)d_ws + sc_off);      // N dwords
    const size_t need = sc_off + (size_t)N * 4;
    float* out = (float*)d_out;

    const int tb = 256;

    if (ws_size >= need) {
        const int nE4   = (E + 3) / 4;       // 4 edges per thread (dst scan)
        const int prep_n = (nE4 > N) ? nE4 : N;
        prep_kernel<<<(prep_n + tb - 1) / tb, tb, 0, stream>>>(
            dst, (const float4*)Km, (const float4*)Vm, E, N,
            row_ptr, ROW, SCt);
        const int grid = (N + 7) / 8;       // 8 nodes per block, 1 per wave
        gat_fused_kernel<<<grid, 512, 0, stream>>>(X, ROW, SCt, Wo, bo,
                                                   src, row_ptr, out, N);
    } else {
        build_row_ptr_kernel<<<(E + tb - 1) / tb, tb, 0, stream>>>(dst, E, N, row_ptr);
        const int grid = (N + 3) / 4;
        gat_node_f32_kernel<<<grid, 256, 0, stream>>>(X, Km, Vm, Wo, bo,
                                                      src, row_ptr, out, N);
    }
}